// Round 2
// baseline (342.726 us; speedup 1.0000x reference)
//
#include <hip/hip_runtime.h>
#include <hip/hip_bf16.h>
#include <math.h>

using bf16 = __hip_bfloat16;
typedef __attribute__((ext_vector_type(8))) short short8;
typedef __attribute__((ext_vector_type(4))) float float4v;

template <typename T> __device__ inline T cvt_out(float v);
template <> __device__ inline float cvt_out<float>(float v) { return v; }
template <> __device__ inline bf16 cvt_out<bf16>(float v) { return __float2bfloat16(v); }

__device__ inline void gload_lds16(const bf16* g, bf16* l) {
    __builtin_amdgcn_global_load_lds(
        (const __attribute__((address_space(1))) void*)g,
        (__attribute__((address_space(3))) void*)l, 16, 0, 0);
}

// ---- fused fp32->bf16 convert for x + 6 weights, one launch ----
struct CvtPack {
    const float* src[7];
    bf16* dst[7];
    int end[7];   // cumulative element ends
};

__global__ __launch_bounds__(256) void cvt_all(CvtPack p) {
    int e = (blockIdx.x * 256 + threadIdx.x) * 4;
    int start = 0;
#pragma unroll
    for (int s = 0; s < 7; ++s) {
        if (e < p.end[s]) {
            int off = e - start;
            float4 v = *(const float4*)(p.src[s] + off);
            bf16* d = p.dst[s] + off;
            d[0] = __float2bfloat16(v.x);
            d[1] = __float2bfloat16(v.y);
            d[2] = __float2bfloat16(v.z);
            d[3] = __float2bfloat16(v.w);
            return;
        }
        start = p.end[s];
    }
}

// ---- split-K reduce: out = act( sum_k p[k*mn+..] + bias ) ----
__device__ inline float4 load4f(const float* p) { return *(const float4*)p; }
__device__ inline float4 load4f(const bf16* p) {
    ushort4 u = *(const ushort4*)p;
    float4 r;
    r.x = __uint_as_float((unsigned)u.x << 16);
    r.y = __uint_as_float((unsigned)u.y << 16);
    r.z = __uint_as_float((unsigned)u.z << 16);
    r.w = __uint_as_float((unsigned)u.w << 16);
    return r;
}
__device__ inline void store4(float* p, float4 v) { *(float4*)p = v; }
__device__ inline void store4(bf16* p, float4 v) {
    p[0] = __float2bfloat16(v.x); p[1] = __float2bfloat16(v.y);
    p[2] = __float2bfloat16(v.z); p[3] = __float2bfloat16(v.w);
}

template <int NK, int ACT, typename InT, typename OutT>
__global__ __launch_bounds__(256) void reduceK(const InT* __restrict__ p,
                                               const float* __restrict__ bias,
                                               OutT* __restrict__ out,
                                               size_t mn, int nmask, int total4) {
    int i = blockIdx.x * 256 + threadIdx.x;
    if (i < total4) {
        int idx = i * 4;
        float4 r = *(const float4*)(bias + (idx & nmask));
#pragma unroll
        for (int k = 0; k < NK; ++k) {
            float4 a = load4f(p + k * mn + idx);
            r.x += a.x; r.y += a.y; r.z += a.z; r.w += a.w;
        }
        if (ACT == 1) {
            r.x = fmaxf(r.x, 0.f); r.y = fmaxf(r.y, 0.f);
            r.z = fmaxf(r.z, 0.f); r.w = fmaxf(r.w, 0.f);
        } else if (ACT == 2) {
            r.x = tanhf(r.x); r.y = tanhf(r.y);
            r.z = tanhf(r.z); r.w = tanhf(r.w);
        }
        store4(out + idx, r);
    }
}

// ---- R12: 8-phase pipelined 256x256 GEMM (T2+T3+T4+T5 combo, m201 template) ----
// 8 waves; wave covers (mh*128 + (wave>>2)*64 + i*16) x (nh*128 + (wave&3)*32 + j*16)
// over quadrants (mh,nh). Per 2-K-tile iteration: 8 phases, each
//   {ds_read frags (A and/or B reused across phases) | stage 1 half-tile
//    -> bar -> lgkmcnt(0) -> 16 MFMA -> bar}
// Half-tile stage schedule (iter j, T=2j):  P1:Ah1(T+1) P2:Bh0(T+1) P3:Ah0(T+2)
//   P4:Bh1(T+2) P5:Ah1(T+2) P6:Bh0(T+2) P7:Ah0(T+3) P8:Bh1(T+3)
// Prologue: tile0 all + tile1{Ah0,Bh1}; vmcnt(4). Steady waits: vmcnt(4) at
// P4/P8 only (never 0 mid-loop). WAR margins >=1 full barrier (verified).
// Requires NT = kcount/64 even and >= 2.
template <int ACT, typename OutT, bool PARTIAL>
__global__ __launch_bounds__(512, 2) void gemm_pipe8(const bf16* __restrict__ A,
                                                     const bf16* __restrict__ W,
                                                     const float* __restrict__ bias,
                                                     OutT* __restrict__ C,
                                                     int M, int N, int K,
                                                     int nbn, int kcount) {
    __shared__ bf16 As[2][2][128 * 64];   // [buf][half] 64 KB
    __shared__ bf16 Bs[2][2][128 * 64];   // 64 KB

    const int bi = blockIdx.x;
    const int xcd = bi & 7, t = bi >> 3;
    const int bn = t % nbn;
    const int bm = xcd + 8 * (t / nbn);
    const int kbeg = PARTIAL ? blockIdx.y * kcount : 0;
    OutT* Cp = PARTIAL ? C + (size_t)blockIdx.y * M * N : C;

    const int tid = threadIdx.x;
    const int wave = tid >> 6, lane = tid & 63;
    const int mwave = (wave >> 2) * 64, nwave = (wave & 3) * 32;
    const int quad = lane >> 4, lrow = lane & 15;
    const int swz = lrow & 7;

    const bf16* Ab = A + (size_t)(bm * 256) * K + kbeg;
    const bf16* Wb = W + (size_t)(bn * 256) * K + kbeg;
    const int NT = kcount >> 6;

    auto stA = [&](int tl, int h) {
        if (tl >= NT) return;
#pragma unroll
        for (int tt = 0; tt < 2; ++tt) {
            int base = tt * 512 + wave * 64;   // wave-uniform LDS base
            int c = base + lane;
            int row = c >> 3, ch = c & 7;
            gload_lds16(Ab + (size_t)(h * 128 + row) * K + tl * 64 + ((ch ^ (row & 7)) << 3),
                        &As[tl & 1][h][0] + base * 8);
        }
    };
    auto stB = [&](int tl, int h) {
        if (tl >= NT) return;
#pragma unroll
        for (int tt = 0; tt < 2; ++tt) {
            int base = tt * 512 + wave * 64;
            int c = base + lane;
            int row = c >> 3, ch = c & 7;
            gload_lds16(Wb + (size_t)(h * 128 + row) * K + tl * 64 + ((ch ^ (row & 7)) << 3),
                        &Bs[tl & 1][h][0] + base * 8);
        }
    };

    float4v acc[2][2][4][2] = {};
    short8 af[4][2], bfv[2][2];

#define LDA8(BUF, MH)                                                         \
    { const bf16* pA = &As[BUF][MH][0];                                       \
      _Pragma("unroll") for (int i = 0; i < 4; ++i)                           \
        _Pragma("unroll") for (int ks = 0; ks < 2; ++ks)                      \
          af[i][ks] = *(const short8*)(pA + (mwave + i * 16 + lrow) * 64 +    \
                                       (((ks * 4 + quad) ^ swz) << 3)); }
#define LDB8(BUF, NH)                                                         \
    { const bf16* pB = &Bs[BUF][NH][0];                                       \
      _Pragma("unroll") for (int j = 0; j < 2; ++j)                           \
        _Pragma("unroll") for (int ks = 0; ks < 2; ++ks)                      \
          bfv[j][ks] = *(const short8*)(pB + (nwave + j * 16 + lrow) * 64 +   \
                                        (((ks * 4 + quad) ^ swz) << 3)); }
#define MM8(MH, NH)                                                           \
    { _Pragma("unroll") for (int ks = 0; ks < 2; ++ks)                        \
        _Pragma("unroll") for (int i = 0; i < 4; ++i)                         \
          _Pragma("unroll") for (int j = 0; j < 2; ++j)                       \
            acc[MH][NH][i][j] = __builtin_amdgcn_mfma_f32_16x16x32_bf16(      \
                af[i][ks], bfv[j][ks], acc[MH][NH][i][j], 0, 0, 0); }
#define SYNC_IN                                                               \
    __builtin_amdgcn_s_barrier();                                             \
    asm volatile("s_waitcnt lgkmcnt(0)" ::: "memory");                        \
    __builtin_amdgcn_sched_barrier(0);                                        \
    __builtin_amdgcn_s_setprio(1);
#define SYNC_OUT                                                              \
    __builtin_amdgcn_s_setprio(0);                                            \
    __builtin_amdgcn_s_barrier();

    // prologue: tile0 fully + tile1 {Ah0, Bh1}
    stA(0, 0); stB(0, 0); stA(0, 1); stB(0, 1);
    stA(1, 0); stB(1, 1);
    if (NT > 1) asm volatile("s_waitcnt vmcnt(4)" ::: "memory");
    else        asm volatile("s_waitcnt vmcnt(0)" ::: "memory");
    __builtin_amdgcn_s_barrier();

    for (int T = 0; T < NT; T += 2) {
        // P1: tile T quad (0,0)
        LDA8(0, 0); LDB8(0, 0); stA(T + 1, 1);
        SYNC_IN; MM8(0, 0); SYNC_OUT;
        // P2: (0,1) — reuse A frags
        LDB8(0, 1); stB(T + 1, 0);
        SYNC_IN; MM8(0, 1); SYNC_OUT;
        // P3: (1,1) — reuse B frags
        LDA8(0, 1); stA(T + 2, 0);
        SYNC_IN; MM8(1, 1); SYNC_OUT;
        // P4: (1,0) — reuse A frags; counted vmcnt
        LDB8(0, 0); stB(T + 2, 1);
        SYNC_IN; MM8(1, 0);
        __builtin_amdgcn_s_setprio(0);
        if (T + 2 < NT) asm volatile("s_waitcnt vmcnt(4)" ::: "memory");
        else            asm volatile("s_waitcnt vmcnt(0)" ::: "memory");
        __builtin_amdgcn_s_barrier();
        // P5: tile T+1 quad (0,0)
        LDA8(1, 0); LDB8(1, 0); stA(T + 2, 1);
        SYNC_IN; MM8(0, 0); SYNC_OUT;
        // P6: (0,1)
        LDB8(1, 1); stB(T + 2, 0);
        SYNC_IN; MM8(0, 1); SYNC_OUT;
        // P7: (1,1)
        LDA8(1, 1); stA(T + 3, 0);
        SYNC_IN; MM8(1, 1); SYNC_OUT;
        // P8: (1,0); counted vmcnt, skip at loop end
        LDB8(1, 0); stB(T + 3, 1);
        SYNC_IN; MM8(1, 0);
        __builtin_amdgcn_s_setprio(0);
        if (T + 2 < NT) {
            asm volatile("s_waitcnt vmcnt(4)" ::: "memory");
            __builtin_amdgcn_s_barrier();
        }
    }
#undef LDA8
#undef LDB8
#undef MM8
#undef SYNC_IN
#undef SYNC_OUT

    // epilogue; C/D layout col=lane&15, row=quad*4+reg (verified mapping)
#pragma unroll
    for (int mh = 0; mh < 2; ++mh)
#pragma unroll
        for (int i = 0; i < 4; ++i) {
            int m0 = bm * 256 + mh * 128 + mwave + i * 16 + quad * 4;
#pragma unroll
            for (int nh = 0; nh < 2; ++nh)
#pragma unroll
                for (int j = 0; j < 2; ++j) {
                    int n = bn * 256 + nh * 128 + nwave + j * 16 + lrow;
                    if constexpr (PARTIAL) {
#pragma unroll
                        for (int r = 0; r < 4; ++r)
                            Cp[(size_t)(m0 + r) * N + n] = cvt_out<OutT>(acc[mh][nh][i][j][r]);
                    } else {
                        float bv = bias[n];
#pragma unroll
                        for (int r = 0; r < 4; ++r) {
                            float v = acc[mh][nh][i][j][r] + bv;
                            if (ACT == 1) v = fmaxf(v, 0.f);
                            else if (ACT == 2) v = tanhf(v);
                            Cp[(size_t)(m0 + r) * N + n] = cvt_out<OutT>(v);
                        }
                    }
                }
        }
}

// ---- 256-thread GEMM: tile (32*WMT)x(32*WNT), 4 waves 2x2, direct stores ----
// (kept for G3 — M=8192,N=1024,K=256: too narrow-K / small for the 256^2 pipe)
template <int ACT, typename OutT, int WMT, int WNT, int BKT, bool PARTIAL>
__global__ __launch_bounds__(256) void gemm_bt(const bf16* __restrict__ A,
                                               const bf16* __restrict__ W,
                                               const float* __restrict__ bias,
                                               OutT* __restrict__ C,
                                               int M, int N, int K,
                                               int nbn, int kcount) {
    constexpr int TBM = 32 * WMT;
    constexpr int TBN = 32 * WNT;
    constexpr int CPR = BKT / 8;
    constexpr int CA = TBM * CPR;
    constexpr int CB = TBN * CPR;

    __shared__ bf16 As[TBM * BKT];
    __shared__ bf16 Bs[TBN * BKT];

    const int bi = blockIdx.x;
    const int xcd = bi & 7, t = bi >> 3;
    const int bn = t % nbn;
    const int bm = xcd + 8 * (t / nbn);
    const int kbeg = PARTIAL ? blockIdx.y * kcount : 0;
    OutT* Cp = PARTIAL ? C + (size_t)blockIdx.y * M * N : C;

    const int tid = threadIdx.x;
    const int wave = tid >> 6, lane = tid & 63;
    const int wm = (wave >> 1) * (16 * WMT), wn = (wave & 1) * (16 * WNT);
    const int quad = lane >> 4, lrow = lane & 15;

    float4v acc[WMT][WNT] = {};
    const size_t arow = (size_t)(bm * TBM) * K;
    const size_t brow = (size_t)(bn * TBN) * K;

    for (int k0 = kbeg; k0 < kbeg + kcount; k0 += BKT) {
        __syncthreads();
#pragma unroll
        for (int tt = 0; tt < CA / 256; ++tt) {
            int base = tt * 256 + wave * 64;       // wave-uniform
            int c = base + lane;
            int row = c / CPR, col = (c % CPR) * 8;
            gload_lds16(A + arow + (size_t)row * K + k0 + col, As + base * 8);
        }
#pragma unroll
        for (int tt = 0; tt < CB / 256; ++tt) {
            int base = tt * 256 + wave * 64;
            int c = base + lane;
            int row = c / CPR, col = (c % CPR) * 8;
            gload_lds16(W + brow + (size_t)row * K + k0 + col, Bs + base * 8);
        }
        __syncthreads();
#pragma unroll
        for (int kk = 0; kk < BKT; kk += 32) {
            short8 af[WMT], bfr[WNT];
#pragma unroll
            for (int i = 0; i < WMT; ++i)
                af[i] = *(const short8*)(As + (wm + i * 16 + lrow) * BKT + kk + quad * 8);
#pragma unroll
            for (int j = 0; j < WNT; ++j)
                bfr[j] = *(const short8*)(Bs + (wn + j * 16 + lrow) * BKT + kk + quad * 8);
#pragma unroll
            for (int i = 0; i < WMT; ++i)
#pragma unroll
                for (int j = 0; j < WNT; ++j)
                    acc[i][j] = __builtin_amdgcn_mfma_f32_16x16x32_bf16(af[i], bfr[j], acc[i][j], 0, 0, 0);
        }
    }

#pragma unroll
    for (int i = 0; i < WMT; ++i) {
        int m0 = bm * TBM + wm + i * 16 + quad * 4;
#pragma unroll
        for (int j = 0; j < WNT; ++j) {
            int n = bn * TBN + wn + j * 16 + lrow;
            if constexpr (PARTIAL) {
#pragma unroll
                for (int r = 0; r < 4; ++r)
                    Cp[(size_t)(m0 + r) * N + n] = cvt_out<OutT>(acc[i][j][r]);
            } else {
                float bv = bias[n];
#pragma unroll
                for (int r = 0; r < 4; ++r) {
                    float v = acc[i][j][r] + bv;
                    if (ACT == 1) v = fmaxf(v, 0.f);
                    else if (ACT == 2) v = tanhf(v);
                    Cp[(size_t)(m0 + r) * N + n] = cvt_out<OutT>(v);
                }
            }
        }
    }
}

// One wave per row: power-norm -> single-tap channel + noise -> LS h_est -> ZF.
__global__ __launch_bounds__(64) void channel_kernel(const float* __restrict__ s,
                                                     const float* __restrict__ h,
                                                     const float* __restrict__ noise,
                                                     float* __restrict__ xr_f,
                                                     bf16* __restrict__ xr_b) {
    const int b = blockIdx.x, lane = threadIdx.x;
    const float* srow = s + (size_t)b * 256;

    float ss = 0.f;
#pragma unroll
    for (int t = 0; t < 4; ++t) {
        float v = srow[lane + 64 * t];
        ss += v * v;
    }
#pragma unroll
    for (int off = 32; off; off >>= 1) ss += __shfl_xor(ss, off);
    const float inv = sqrtf(128.0f) / sqrtf(ss);

    const float hre = h[0], him = h[1];

    float yre[2], yim[2];
    float nre = 0.f, nim = 0.f, den = 0.f;
#pragma unroll
    for (int t = 0; t < 2; ++t) {
        int c = lane + 64 * t;
        float tr = srow[2 * c] * inv, ti = srow[2 * c + 1] * inv;
        float yr = hre * tr - him * ti + noise[(size_t)b * 256 + 2 * c];
        float yi = hre * ti + him * tr + noise[(size_t)b * 256 + 2 * c + 1];
        yre[t] = yr; yim[t] = yi;
        nre += yr * tr + yi * ti;
        nim += yi * tr - yr * ti;
        den += tr * tr + ti * ti;
    }
#pragma unroll
    for (int off = 32; off; off >>= 1) {
        nre += __shfl_xor(nre, off);
        nim += __shfl_xor(nim, off);
        den += __shfl_xor(den, off);
    }
    const float her = nre / den, hei = nim / den;
    const float d2 = her * her + hei * hei + 1e-12f;

#pragma unroll
    for (int t = 0; t < 2; ++t) {
        int c = lane + 64 * t;
        float xre = (yre[t] * her + yim[t] * hei) / d2;
        float xim = (yim[t] * her - yre[t] * hei) / d2;
        xr_f[(size_t)b * 256 + 2 * c] = xre;
        xr_f[(size_t)b * 256 + 2 * c + 1] = xim;
        xr_b[(size_t)b * 256 + 2 * c] = __float2bfloat16(xre);
        xr_b[(size_t)b * 256 + 2 * c + 1] = __float2bfloat16(xim);
    }
}

// One wave per row: h_inv = g2 @ w_rtn3^T + b_rtn3 (N=6), 3-tap complex FIR.
__global__ __launch_bounds__(64) void rtn_taps_conv(const bf16* __restrict__ g2,
                                                    const float* __restrict__ wr3,
                                                    const float* __restrict__ br3,
                                                    const float* __restrict__ xr_f,
                                                    bf16* __restrict__ xr2) {
    const int b = blockIdx.x, lane = threadIdx.x;
    const bf16* grow = g2 + (size_t)b * 1024;

    float acc[6] = {0.f, 0.f, 0.f, 0.f, 0.f, 0.f};
#pragma unroll
    for (int t = 0; t < 16; ++t) {
        int k = lane + 64 * t;
        float gv = __bfloat162float(grow[k]);
#pragma unroll
        for (int j = 0; j < 6; ++j) acc[j] += gv * wr3[j * 1024 + k];
    }
#pragma unroll
    for (int j = 0; j < 6; ++j)
#pragma unroll
        for (int off = 32; off; off >>= 1) acc[j] += __shfl_xor(acc[j], off);

    float tre[3], tim[3];
#pragma unroll
    for (int l = 0; l < 3; ++l) {
        tre[l] = acc[2 * l] + br3[2 * l];
        tim[l] = acc[2 * l + 1] + br3[2 * l + 1];
    }

    const float* xrow = xr_f + (size_t)b * 256;
#pragma unroll
    for (int t = 0; t < 2; ++t) {
        int c = lane + 64 * t;
        float ore = 0.f, oim = 0.f;
#pragma unroll
        for (int l = 0; l < 3; ++l) {
            int cc = c - l;
            if (cc >= 0) {
                float xre = xrow[2 * cc], xim = xrow[2 * cc + 1];
                ore += tre[l] * xre - tim[l] * xim;
                oim += tre[l] * xim + tim[l] * xre;
            }
        }
        xr2[(size_t)b * 256 + 2 * c] = __float2bfloat16(ore);
        xr2[(size_t)b * 256 + 2 * c + 1] = __float2bfloat16(oim);
    }
}

extern "C" void kernel_launch(void* const* d_in, const int* in_sizes, int n_in,
                              void* d_out, int out_size, void* d_ws, size_t ws_size,
                              hipStream_t stream) {
    constexpr int B = 8192, D_IN = 512, H1 = 4096, CH = 256, HR = 1024, H2 = 4096, DOUT = 512;

    const float* x   = (const float*)d_in[0];
    const float* w1  = (const float*)d_in[1];
    const float* b1  = (const float*)d_in[2];
    const float* w2  = (const float*)d_in[3];
    const float* b2  = (const float*)d_in[4];
    const float* wr1 = (const float*)d_in[5];
    const float* br1 = (const float*)d_in[6];
    const float* wr2 = (const float*)d_in[7];
    const float* br2 = (const float*)d_in[8];
    const float* wr3 = (const float*)d_in[9];
    const float* br3 = (const float*)d_in[10];
    const float* w3  = (const float*)d_in[11];
    const float* b3  = (const float*)d_in[12];
    const float* w4  = (const float*)d_in[13];
    const float* b4  = (const float*)d_in[14];
    const float* h   = (const float*)d_in[15];
    const float* noise = (const float*)d_in[16];

    // ---- workspace layout (bytes); liveness traced per launch ----
    char* ws = (char*)d_ws;
    bf16*  a    = (bf16*)(ws + 0);          // 64 MB: G1 out, G2 in; dead after G2
    float* sF   = (float*)(ws + 0);         // 8 MB: reduce(G2) out, channel in (a dead)
    bf16*  g1   = (bf16*)(ws + 0);          // 16 MB: G3 out (sF dead post-channel)
    bf16*  g2   = (bf16*)(ws + 16777216);   // 16 MB: reduce(G4) out, rtn in
    bf16*  g4P  = (bf16*)(ws + 33554432);   // 2 x 16 MB: G4 bf16 partials (tbuf region dead during G4)
    bf16*  tbuf = (bf16*)(ws + 0);          // 64 MB: G5 out (g1/g2 dead post-rtn)
    bf16*  w1B  = (bf16*)(ws + 67108864);   // 4 MB
    bf16*  w2B  = (bf16*)(ws + 71303168);   // 2 MB
    bf16*  wr1B = (bf16*)(ws + 73400320);   // 0.5 MB
    bf16*  wr2B = (bf16*)(ws + 73924608);   // 2 MB
    bf16*  w3B  = (bf16*)(ws + 76021760);   // 2 MB
    bf16*  w4B  = (bf16*)(ws + 78118912);   // 4 MB
    bf16*  xB   = (bf16*)(ws + 82313216);   // 8 MB: bf16(x), dead after G1
    bf16*  g2P  = (bf16*)(ws + 82313216);   // 8 x 4 MB: G2 bf16 partials
    float* xrF  = (float*)(ws + 99090432);  // 8 MB: channel out, rtn in
    bf16*  xrB  = (bf16*)(ws + 107479040);  // 4 MB: channel out, G3 in
    bf16*  xr2  = (bf16*)(ws + 111673344);  // 4 MB: rtn out, G5 in
    bf16*  g6P  = (bf16*)(ws + 82313216);   // 4 x 8 MB: G6 partials (xrF/xrB/xr2 dead at G6)

    dim3 blk(256);

    // ---- single fused fp32->bf16 convert ----
    CvtPack p;
    const float* srcs[7] = {x, w1, w2, wr1, wr2, w3, w4};
    bf16* dsts[7] = {xB, w1B, w2B, wr1B, wr2B, w3B, w4B};
    int ns[7] = {B * D_IN, H1 * D_IN, CH * H1, HR * CH, HR * HR, H2 * CH, DOUT * H2};
    int cum = 0;
    for (int i = 0; i < 7; ++i) { p.src[i] = srcs[i]; p.dst[i] = dsts[i]; cum += ns[i]; p.end[i] = cum; }
    cvt_all<<<(cum / 4 + 255) / 256, blk, 0, stream>>>(p);

    // ---- encoder ----
    // G1: 8-phase 256x256, grid 32x16=512, NT=8
    gemm_pipe8<1, bf16, false><<<dim3(32 * 16), dim3(512), 0, stream>>>(
        xB, w1B, b1, a, B, H1, D_IN, 16, D_IN);
    // G2: 8-phase, split-K=8 (kc=512, NT=8), grid (32,8)=256, bf16 partials
    gemm_pipe8<0, bf16, true><<<dim3(32, 8), dim3(512), 0, stream>>>(
        a, w2B, nullptr, g2P, B, CH, H1, 1, H1 / 8);
    reduceK<8, 0, bf16, float><<<(B * CH / 4 + 255) / 256, blk, 0, stream>>>(
        g2P, b2, sF, (size_t)B * CH, CH - 1, B * CH / 4);
    // ---- channel + ZF (fp32) ----
    channel_kernel<<<B, 64, 0, stream>>>(sF, h, noise, xrF, xrB);
    // ---- RTN ----
    // G3: 128x64, nbm=64, nbn=16, grid 1024 [R9-proven]
    gemm_bt<2, bf16, 4, 2, 64, false><<<64 * 16, blk, 0, stream>>>(
        xrB, wr1B, br1, g1, B, HR, CH, 16, CH);
    // G4: 8-phase 256x256, split-K=2 (kc=512, NT=8), grid (128,2)=256,
    // bf16 partials; tanh folded into reduce
    gemm_pipe8<0, bf16, true><<<dim3(32 * 4, 2), dim3(512), 0, stream>>>(
        g1, wr2B, nullptr, g4P, B, HR, HR, 4, HR / 2);
    reduceK<2, 2, bf16, bf16><<<(B * HR / 4 + 255) / 256, blk, 0, stream>>>(
        g4P, br2, g2, (size_t)B * HR, HR - 1, B * HR / 4);
    rtn_taps_conv<<<B, 64, 0, stream>>>(g2, wr3, br3, xrF, xr2);
    // ---- decoder ----
    // G5: 8-phase 256x256, grid 512, NT=4
    gemm_pipe8<1, bf16, false><<<dim3(32 * 16), dim3(512), 0, stream>>>(
        xr2, w3B, b3, tbuf, B, H2, CH, 16, CH);
    // G6: 8-phase, split-K=4 (kc=1024, NT=16), grid (64,4)=256, bf16 partials
    gemm_pipe8<0, bf16, true><<<dim3(32 * 2, 4), dim3(512), 0, stream>>>(
        tbuf, w4B, nullptr, g6P, B, DOUT, H2, 2, H2 / 4);
    reduceK<4, 0, bf16, float><<<(B * DOUT / 4 + 255) / 256, blk, 0, stream>>>(
        g6P, b4, (float*)d_out, (size_t)B * DOUT, DOUT - 1, B * DOUT / 4);
}